// Round 13
// baseline (655.664 us; speedup 1.0000x reference)
//
#include <hip/hip_runtime.h>
#include <math.h>

// ---------------------------------------------------------------------------
// TemporalGraphEncoder: N=50000, E=1.6M, D=128, H=4, C=32, HOPS=3
// r13: (1) ODE: two-chunk interleave per block (ILP fills the per-stage
//      latency chain that occupancy knobs r9-r12 couldn't); non-persistent.
//      (2) hop3 fused with hop-attention combine (final2_k eliminated).
// ---------------------------------------------------------------------------

typedef __attribute__((ext_vector_type(8))) short bf16x8;
typedef __attribute__((ext_vector_type(4))) float f32x4;

#define BSN 256   // nodes per bucket in CSR build (bucket id = dst >> 8)

__device__ __forceinline__ float gelu_f(float x) {           // exact (erf)
    return 0.5f * x * (1.0f + erff(x * 0.70710678118654752f));
}
__device__ __forceinline__ float gelu_sig(float x) {         // tanh-form, folded
    float x2 = x * x;
    float f = fmaf(-0.0713548162f, x2, -1.5957691216f);
    float e = __expf(x * f);
    return x * __builtin_amdgcn_rcpf(1.0f + e);
}
__device__ __forceinline__ unsigned pack_bf16(float a, float b) {
    unsigned ua = __float_as_uint(a), ub = __float_as_uint(b);
    ua += 0x7fffu + ((ua >> 16) & 1u);
    ub += 0x7fffu + ((ub >> 16) & 1u);
    return (ua >> 16) | (ub & 0xffff0000u);
}
__device__ __forceinline__ unsigned short bfbits(float x) {
    unsigned u = __float_as_uint(x);
    u += 0x7fffu + ((u >> 16) & 1u);
    return (unsigned short)(u >> 16);
}
__device__ __forceinline__ float bf_lo(unsigned u) { return __uint_as_float(u << 16); }
__device__ __forceinline__ float bf_hi(unsigned u) { return __uint_as_float(u & 0xffff0000u); }
// XOR swizzle for 256B-row-stride LDS tiles (16B granule)
__device__ __forceinline__ int swz(int byte) { return byte ^ (((byte >> 8) & 15) << 4); }

// ---------------------- spectral norm (power iteration) --------------------
__launch_bounds__(128, 1)
__global__ void sn_k(const float* __restrict__ Win, const float* __restrict__ Wode,
                     float* __restrict__ WnIn, float* __restrict__ WnOde)
{
    __shared__ float Ws[128 * 128];
    __shared__ float Wt[128 * 128];
    __shared__ float red[128];
    const float* W  = (blockIdx.x == 0) ? Win  : Wode;
    float*       Wn = (blockIdx.x == 0) ? WnIn : WnOde;
    const int t = threadIdx.x;

    for (int i = t * 4; i < 16384; i += 512) {
        float4 v = *(const float4*)&W[i];
        *(float4*)&Ws[i] = v;
        int r = i >> 7, c = i & 127;
        Wt[(c + 0) * 128 + r] = v.x;
        Wt[(c + 1) * 128 + r] = v.y;
        Wt[(c + 2) * 128 + r] = v.z;
        Wt[(c + 3) * 128 + r] = v.w;
    }
    __syncthreads();

    float u = 0.088388347648318447f;  // 1/sqrt(128)
    float v = 0.0f;
    for (int it = 0; it < 5; it++) {
        red[t] = u; __syncthreads();
        float vv = 0.f;
        for (int i = 0; i < 128; i++) vv = fmaf(Ws[i * 128 + t], red[i], vv);
        __syncthreads();
        red[t] = vv * vv; __syncthreads();
        for (int s = 64; s > 0; s >>= 1) { if (t < s) red[t] += red[t + s]; __syncthreads(); }
        float nv = sqrtf(red[0]) + 1e-12f;
        v = vv / nv;
        __syncthreads();
        red[t] = v; __syncthreads();
        float uu = 0.f;
        for (int i = 0; i < 128; i++) uu = fmaf(Wt[i * 128 + t], red[i], uu);
        __syncthreads();
        red[t] = uu * uu; __syncthreads();
        for (int s = 64; s > 0; s >>= 1) { if (t < s) red[t] += red[t + s]; __syncthreads(); }
        float nu = sqrtf(red[0]) + 1e-12f;
        u = uu / nu;
        __syncthreads();
    }
    red[t] = v; __syncthreads();
    float wv = 0.f;
    for (int i = 0; i < 128; i++) wv = fmaf(Wt[i * 128 + t], red[i], wv);
    __syncthreads();
    red[t] = u * wv; __syncthreads();
    for (int s = 64; s > 0; s >>= 1) { if (t < s) red[t] += red[t + s]; __syncthreads(); }
    float inv = 1.0f / (red[0] + 1e-12f);
    __syncthreads();
    for (int i = t * 4; i < 16384; i += 512) {
        float4 w = *(const float4*)&Ws[i];
        w.x *= inv; w.y *= inv; w.z *= inv; w.w *= inv;
        *(float4*)&Wn[i] = w;
    }
}

// ---------------- pack W_ode^T into B-fragment order (bf16, global) --------
__launch_bounds__(256)
__global__ void frag_k(const float* __restrict__ Wn, unsigned short* __restrict__ frag)
{
    int f = blockIdx.x * 256 + threadIdx.x;
    if (f >= 2048) return;
    int lane = f & 63, ks = (f >> 6) & 3, m = f >> 8;
    int cl = lane & 15, lg = lane >> 4;
    unsigned short tmp[8];
#pragma unroll
    for (int j = 0; j < 8; j++)
        tmp[j] = bfbits(Wn[(ks * 32 + lg * 8 + j) * 128 + m * 16 + cl]);
    *(uint4*)&frag[(size_t)f * 8] = *(uint4*)tmp;
}

// ------------------------------ CSR build ----------------------------------
__global__ void hist_k(const int* __restrict__ dst, int* __restrict__ deg, int E, int N)
{
    int e = blockIdx.x * blockDim.x + threadIdx.x;
    if (e < E) {
        int d = dst[e];
        d = (d < 0) ? 0 : (d >= N ? N - 1 : d);
        atomicAdd(&deg[d], 1);
    }
}

__launch_bounds__(1024, 1)
__global__ void scan_k(const int* __restrict__ deg, int* __restrict__ offs, int n)
{
    __shared__ int part[1024];
    const int t = threadIdx.x;
    const int chunk = (n + 1023) >> 10;
    int lo = t * chunk; if (lo > n) lo = n;
    int hi = lo + chunk; if (hi > n) hi = n;
    int s = 0;
    for (int i = lo; i < hi; i++) s += deg[i];
    part[t] = s; __syncthreads();
    for (int d = 1; d < 1024; d <<= 1) {
        int v = (t >= d) ? part[t - d] : 0;
        __syncthreads();
        part[t] += v;
        __syncthreads();
    }
    int run = (t == 0) ? 0 : part[t - 1];
    for (int i = lo; i < hi; i++) { offs[i] = run; run += deg[i]; }
    if (t == 1023) offs[n] = run;
}

__global__ void binit_k(const int* __restrict__ offs, int* __restrict__ bcur, int N, int nb)
{
    int b = blockIdx.x * blockDim.x + threadIdx.x;
    if (b < nb) {
        int n = b * BSN; if (n > N) n = N;
        bcur[b] = offs[n];
    }
}

// pass A: block-level multisplit of edges into bucket regions of pairbuf.
__launch_bounds__(256, 2)
__global__ void scatA_k(const int* __restrict__ src, const int* __restrict__ dst,
                        int* __restrict__ bcur, uint2* __restrict__ pairbuf, int E, int N)
{
    __shared__ int cnt[256];
    __shared__ int sc[256];
    __shared__ int ebase[256];
    __shared__ int delta[256];
    __shared__ uint2 pr[4096];
    __shared__ unsigned char bid[4096];
    const int t = threadIdx.x;
    const int e0 = blockIdx.x * 4096;

    int s[16], d[16], rk[16], bb[16];
    cnt[t] = 0;
    __syncthreads();
#pragma unroll
    for (int i = 0; i < 16; i++) {
        int e = e0 + i * 256 + t;
        if (e < E) {
            int dd = dst[e]; dd = (dd < 0) ? 0 : (dd >= N ? N - 1 : dd);
            int ss = src[e]; ss = (ss < 0) ? 0 : (ss >= N ? N - 1 : ss);
            s[i] = ss; d[i] = dd; bb[i] = dd >> 8;
            rk[i] = atomicAdd(&cnt[bb[i]], 1);
        } else bb[i] = -1;
    }
    __syncthreads();
    sc[t] = cnt[t]; __syncthreads();
    for (int st = 1; st < 256; st <<= 1) {
        int v = (t >= st) ? sc[t - st] : 0;
        __syncthreads();
        sc[t] += v;
        __syncthreads();
    }
    int excl = sc[t] - cnt[t];
    int gbase = (cnt[t] > 0) ? atomicAdd(&bcur[t], cnt[t]) : 0;
    ebase[t] = excl;
    delta[t] = gbase - excl;
    __syncthreads();
#pragma unroll
    for (int i = 0; i < 16; i++) {
        if (bb[i] >= 0) {
            int slot = ebase[bb[i]] + rk[i];
            pr[slot] = make_uint2((unsigned)s[i], (unsigned)d[i]);
            bid[slot] = (unsigned char)bb[i];
        }
    }
    __syncthreads();
    const int total = sc[255];
    for (int i2 = t; i2 < total; i2 += 256) {
        int b = bid[i2];
        pairbuf[delta[b] + i2] = pr[i2];
    }
}

// pass B: one block per bucket; finalize col with LDS node cursors.
__launch_bounds__(256, 4)
__global__ void scatB_k(const uint2* __restrict__ pairbuf, const int* __restrict__ offs,
                        int* __restrict__ col, int N)
{
    __shared__ int cur[BSN];
    const int b = blockIdx.x;
    const int n0 = b * BSN;
    const int t = threadIdx.x;
    int nn = N - n0; if (nn > BSN) nn = BSN;
    if (t < nn) cur[t] = offs[n0 + t];
    __syncthreads();
    const int es = offs[n0], ee = offs[n0 + nn];
    for (int e = es + t; e < ee; e += 256) {
        uint2 p = pairbuf[e];
        int pos = atomicAdd(&cur[(int)p.y - n0], 1);
        col[pos] = (int)p.x;
    }
}

// ------------------------ GEMM 128 (bf16 MFMA) -----------------------------
__launch_bounds__(256, 2)
__global__ void gemm_mfma_k(const float* __restrict__ in, const float* __restrict__ W,
                            const float* __restrict__ bias, float* __restrict__ out_f32,
                            unsigned short* __restrict__ out_bf, int nrows, int mode,
                            const float* __restrict__ a_s, const float* __restrict__ a_d,
                            float* __restrict__ als, float* __restrict__ ald)
{
    __shared__ unsigned short Wt[128 * 128];
    __shared__ unsigned short As[128 * 128];
    const int t = threadIdx.x;
    const int w = t >> 6, lane = t & 63;
    const int cl = lane & 15, lg = lane >> 4;
    const int r0 = blockIdx.x * 128;

    for (int i = t; i < 16384; i += 256) {
        int k = i >> 7, c = i & 127;
        *(unsigned short*)((char*)Wt + swz((c << 8) + (k << 1))) = bfbits(W[i]);
    }
    for (int i2 = t; i2 < 4096; i2 += 256) {
        int r = i2 >> 5, k0 = (i2 & 31) * 4;
        int rc = r0 + r; if (rc > nrows - 1) rc = nrows - 1;
        float4 v = *(const float4*)&in[(size_t)rc * 128 + k0];
        *(uint2*)((char*)As + swz((r << 8) + (k0 << 1))) =
            make_uint2(pack_bf16(v.x, v.y), pack_bf16(v.z, v.w));
    }
    __syncthreads();

    bf16x8 af[2][4];
#pragma unroll
    for (int rt = 0; rt < 2; rt++)
#pragma unroll
        for (int ks = 0; ks < 4; ks++)
            af[rt][ks] = *(const bf16x8*)((char*)As +
                           swz((w * 32 + rt * 16 + cl) * 256 + ks * 64 + lg * 16));

    f32x4 acc[2][8];
#pragma unroll
    for (int rt = 0; rt < 2; rt++)
#pragma unroll
        for (int n = 0; n < 8; n++) acc[rt][n] = (f32x4){0.f, 0.f, 0.f, 0.f};

#pragma unroll
    for (int n = 0; n < 8; n++) {
#pragma unroll
        for (int ks = 0; ks < 4; ks++) {
            bf16x8 bf = *(const bf16x8*)((char*)Wt +
                          swz((n * 16 + cl) * 256 + ks * 64 + lg * 16));
            acc[0][n] = __builtin_amdgcn_mfma_f32_16x16x32_bf16(af[0][ks], bf, acc[0][n], 0, 0, 0);
            acc[1][n] = __builtin_amdgcn_mfma_f32_16x16x32_bf16(af[1][ks], bf, acc[1][n], 0, 0, 0);
        }
    }

    if (mode == 0) {
        float asv[4][2], adv[4][2];
#pragma unroll
        for (int h = 0; h < 4; h++) {
            asv[h][0] = a_s[h * 32 + cl];      asv[h][1] = a_s[h * 32 + 16 + cl];
            adv[h][0] = a_d[h * 32 + cl];      adv[h][1] = a_d[h * 32 + 16 + cl];
        }
#pragma unroll
        for (int rt = 0; rt < 2; rt++) {
#pragma unroll
            for (int q = 0; q < 4; q++) {
                int row = r0 + w * 32 + rt * 16 + lg * 4 + q;
                float sh[4], dh[4];
#pragma unroll
                for (int h = 0; h < 4; h++) {
                    sh[h] = acc[rt][2 * h][q] * asv[h][0] + acc[rt][2 * h + 1][q] * asv[h][1];
                    dh[h] = acc[rt][2 * h][q] * adv[h][0] + acc[rt][2 * h + 1][q] * adv[h][1];
                }
#pragma unroll
                for (int mk = 1; mk < 16; mk <<= 1) {
#pragma unroll
                    for (int h = 0; h < 4; h++) {
                        sh[h] += __shfl_xor(sh[h], mk);
                        dh[h] += __shfl_xor(dh[h], mk);
                    }
                }
                if (cl == 0 && row < nrows) {
#pragma unroll
                    for (int h = 0; h < 4; h++) {
                        als[(size_t)row * 4 + h] = sh[h];
                        ald[(size_t)row * 4 + h] = dh[h];
                    }
                }
            }
#pragma unroll
            for (int q = 0; q < 4; q++) {
                int row = r0 + w * 32 + rt * 16 + lg * 4 + q;
                if (row < nrows) {
#pragma unroll
                    for (int n = 0; n < 8; n++)
                        out_bf[(size_t)row * 128 + n * 16 + cl] = bfbits(acc[rt][n][q]);
                }
            }
        }
    } else {
        float bc[8];
#pragma unroll
        for (int n = 0; n < 8; n++) bc[n] = bias[n * 16 + cl];
#pragma unroll
        for (int rt = 0; rt < 2; rt++)
#pragma unroll
            for (int q = 0; q < 4; q++) {
                int row = r0 + w * 32 + rt * 16 + lg * 4 + q;
                if (row < nrows) {
#pragma unroll
                    for (int n = 0; n < 8; n++)
                        out_f32[(size_t)row * 128 + n * 16 + cl] =
                            gelu_f(acc[rt][n][q] + bc[n]);
                }
            }
    }
}

// ----------------------- GAT aggregation (32-lane node groups) -------------
__launch_bounds__(256)
__global__ void gat_agg2_k(const unsigned* __restrict__ xhbf, const float* __restrict__ als,
                           const float* __restrict__ ald, const int* __restrict__ col,
                           const int* __restrict__ offs, const float* __restrict__ bias,
                           const float* __restrict__ g, const float* __restrict__ be,
                           float* __restrict__ hout, int nnodes)
{
    __shared__ float alph[8][32][4];
    __shared__ int   scol[8][32];
    const int gq = threadIdx.x >> 5;
    const int n = blockIdx.x * 8 + gq;
    if (n >= nnodes) return;
    const int l = threadIdx.x & 31;
    const int e0 = offs[n], e1 = offs[n + 1];
    const float4 aldv = *(const float4*)&ald[(size_t)n * 4];

    float m0 = -1e30f, m1 = -1e30f, m2 = -1e30f, m3 = -1e30f;
    float s0 = 0.f, s1 = 0.f, s2 = 0.f, s3 = 0.f;
    for (int i = e0 + l; i < e1; i += 32) {
        int sv = col[i];
        float4 av = *(const float4*)&als[(size_t)sv * 4];
        float l0 = av.x + aldv.x; l0 = l0 > 0.f ? l0 : 0.2f * l0;
        float l1 = av.y + aldv.y; l1 = l1 > 0.f ? l1 : 0.2f * l1;
        float l2 = av.z + aldv.z; l2 = l2 > 0.f ? l2 : 0.2f * l2;
        float l3 = av.w + aldv.w; l3 = l3 > 0.f ? l3 : 0.2f * l3;
        float M;
        M = fmaxf(m0, l0); s0 = s0 * __expf(m0 - M) + __expf(l0 - M); m0 = M;
        M = fmaxf(m1, l1); s1 = s1 * __expf(m1 - M) + __expf(l1 - M); m1 = M;
        M = fmaxf(m2, l2); s2 = s2 * __expf(m2 - M) + __expf(l2 - M); m2 = M;
        M = fmaxf(m3, l3); s3 = s3 * __expf(m3 - M) + __expf(l3 - M); m3 = M;
    }
#pragma unroll
    for (int mk = 1; mk < 32; mk <<= 1) {
        float mo, so, M;
        mo = __shfl_xor(m0, mk); so = __shfl_xor(s0, mk);
        M = fmaxf(m0, mo); s0 = s0 * __expf(m0 - M) + so * __expf(mo - M); m0 = M;
        mo = __shfl_xor(m1, mk); so = __shfl_xor(s1, mk);
        M = fmaxf(m1, mo); s1 = s1 * __expf(m1 - M) + so * __expf(mo - M); m1 = M;
        mo = __shfl_xor(m2, mk); so = __shfl_xor(s2, mk);
        M = fmaxf(m2, mo); s2 = s2 * __expf(m2 - M) + so * __expf(mo - M); m2 = M;
        mo = __shfl_xor(m3, mk); so = __shfl_xor(s3, mk);
        M = fmaxf(m3, mo); s3 = s3 * __expf(m3 - M) + so * __expf(mo - M); m3 = M;
    }
    const float i0 = 1.f / (s0 + 1e-16f), i1 = 1.f / (s1 + 1e-16f);
    const float i2 = 1.f / (s2 + 1e-16f), i3 = 1.f / (s3 + 1e-16f);

    const int hh = l >> 3;
    float a0 = 0.f, a1 = 0.f, a2 = 0.f, a3 = 0.f;
    for (int base = e0; base < e1; base += 32) {
        int idx = base + l;
        if (idx < e1) {
            int sv = col[idx];
            float4 av = *(const float4*)&als[(size_t)sv * 4];
            float l0 = av.x + aldv.x; l0 = l0 > 0.f ? l0 : 0.2f * l0;
            float l1 = av.y + aldv.y; l1 = l1 > 0.f ? l1 : 0.2f * l1;
            float l2 = av.z + aldv.z; l2 = l2 > 0.f ? l2 : 0.2f * l2;
            float l3 = av.w + aldv.w; l3 = l3 > 0.f ? l3 : 0.2f * l3;
            float4 a4;
            a4.x = __expf(l0 - m0) * i0;
            a4.y = __expf(l1 - m1) * i1;
            a4.z = __expf(l2 - m2) * i2;
            a4.w = __expf(l3 - m3) * i3;
            *(float4*)&alph[gq][l][0] = a4;
            scol[gq][l] = sv;
        }
        int cnt = e1 - base; if (cnt > 32) cnt = 32;
#pragma unroll 4
        for (int j = 0; j < cnt; j++) {
            int sj = scol[gq][j];
            float aj = alph[gq][j][hh];
            uint2 u = *(const uint2*)&xhbf[(size_t)sj * 64 + l * 2];
            a0 = fmaf(aj, bf_lo(u.x), a0);
            a1 = fmaf(aj, bf_hi(u.x), a1);
            a2 = fmaf(aj, bf_lo(u.y), a2);
            a3 = fmaf(aj, bf_hi(u.y), a3);
        }
    }

    const int c0 = l * 4;
    float4 bv = *(const float4*)&bias[c0];
    float v0 = gelu_f(a0 + bv.x);
    float v1 = gelu_f(a1 + bv.y);
    float v2 = gelu_f(a2 + bv.z);
    float v3 = gelu_f(a3 + bv.w);
    float sum = v0 + v1 + v2 + v3;
#pragma unroll
    for (int mk = 1; mk < 32; mk <<= 1) sum += __shfl_xor(sum, mk);
    float mean = sum * (1.0f / 128.0f);
    float d0 = v0 - mean, d1 = v1 - mean, d2 = v2 - mean, d3 = v3 - mean;
    float vs = d0 * d0 + d1 * d1 + d2 * d2 + d3 * d3;
#pragma unroll
    for (int mk = 1; mk < 32; mk <<= 1) vs += __shfl_xor(vs, mk);
    float rstd = rsqrtf(vs * (1.0f / 128.0f) + 1e-5f);
    float4 gv = *(const float4*)&g[c0];
    float4 ev = *(const float4*)&be[c0];
    float4 o;
    o.x = d0 * rstd * gv.x + ev.x;
    o.y = d1 * rstd * gv.y + ev.y;
    o.z = d2 * rstd * gv.z + ev.z;
    o.w = d3 * rstd * gv.w + ev.w;
    *(float4*)&hout[(size_t)n * 128 + c0] = o;
}

// ----------------------- fused RK4 ODE (bf16 MFMA, 2-chunk interleave) -----
// 128 threads = one wave-pair; block handles chunks 2b and 2b+1 interleaved
// so chunk B's independent work fills chunk A's latency within the wave.
// B-frags in registers from pre-packed global buffer. LDS 16KB (2 x dbuf).
__launch_bounds__(128, 2)
__global__ void ode_mfma_k(const float* __restrict__ yin,
                           const unsigned short* __restrict__ frag,
                           const float* __restrict__ bias,
                           unsigned short* __restrict__ ybf,
                           int nrows, int nchunks)
{
    __shared__ unsigned short tl[2][2][16 * 128];   // [chunk][dbuf], 4KB each
    const int t = threadIdx.x;
    const int hf = t >> 6, lane = t & 63;
    const int cl = lane & 15, lg = lane >> 4;

    float bcol[4];
#pragma unroll
    for (int n = 0; n < 4; n++) bcol[n] = bias[(hf * 4 + n) * 16 + cl];

    bf16x8 bfr[4][4];
#pragma unroll
    for (int n = 0; n < 4; n++)
#pragma unroll
        for (int ks = 0; ks < 4; ks++)
            bfr[n][ks] = *(const bf16x8*)&frag[((size_t)(((hf * 4 + n) * 4 + ks) * 64 + lane)) * 8];

    int radr[4], wadr[4][4];
#pragma unroll
    for (int ks = 0; ks < 4; ks++)
        radr[ks] = swz(cl * 256 + ks * 64 + lg * 16);
#pragma unroll
    for (int n = 0; n < 4; n++)
#pragma unroll
        for (int q = 0; q < 4; q++)
            wadr[n][q] = swz((lg * 4 + q) * 256 + ((hf * 4 + n) * 16 + cl) * 2);

    const float dt = 0.25f;
    int cA = blockIdx.x * 2, cB = cA + 1;
    if (cA > nchunks - 1) cA = nchunks - 1;
    if (cB > nchunks - 1) cB = nchunks - 1;
    const int rA = cA * 16, rB = cB * 16;

    char* tA0 = (char*)&tl[0][0][0];
    char* tA1 = (char*)&tl[0][1][0];
    char* tB0 = (char*)&tl[1][0][0];
    char* tB1 = (char*)&tl[1][1][0];

    // stage y -> both t-buffers
    for (int i2 = t; i2 < 512; i2 += 128) {
        int r = i2 >> 5, k0 = (i2 & 31) * 4;
        int ra = rA + r; if (ra > nrows - 1) ra = nrows - 1;
        int rb = rB + r; if (rb > nrows - 1) rb = nrows - 1;
        float4 va = *(const float4*)&yin[(size_t)ra * 128 + k0];
        float4 vb = *(const float4*)&yin[(size_t)rb * 128 + k0];
        int ad = swz(r * 256 + k0 * 2);
        *(uint2*)(tA0 + ad) = make_uint2(pack_bf16(va.x, va.y), pack_bf16(va.z, va.w));
        *(uint2*)(tB0 + ad) = make_uint2(pack_bf16(vb.x, vb.y), pack_bf16(vb.z, vb.w));
    }
    float yvA[4][4], avA[4][4], yvB[4][4], avB[4][4];
#pragma unroll
    for (int q = 0; q < 4; q++) {
        int ra = rA + lg * 4 + q; if (ra > nrows - 1) ra = nrows - 1;
        int rb = rB + lg * 4 + q; if (rb > nrows - 1) rb = nrows - 1;
        const float* rpa = &yin[(size_t)ra * 128 + hf * 64 + cl];
        const float* rpb = &yin[(size_t)rb * 128 + hf * 64 + cl];
#pragma unroll
        for (int n = 0; n < 4; n++) {
            yvA[n][q] = rpa[n * 16]; avA[n][q] = yvA[n][q];
            yvB[n][q] = rpb[n * 16]; avB[n][q] = yvB[n][q];
        }
    }
    __syncthreads();

    char* pcA = tA0; char* pnA = tA1;
    char* pcB = tB0; char* pnB = tB1;
#pragma unroll 1
    for (int step = 0; step < 4; step++) {
#pragma unroll 1
        for (int st = 0; st < 4; st++) {
            const float ca = (st == 0 || st == 3) ? dt / 6.f : dt / 3.f;
            const float ct = (st < 2) ? dt * 0.5f : dt;
            const bool last = (st == 3);
            bf16x8 afA[4], afB[4];
#pragma unroll
            for (int ks = 0; ks < 4; ks++) {
                afA[ks] = *(const bf16x8*)(pcA + radr[ks]);
                afB[ks] = *(const bf16x8*)(pcB + radr[ks]);
            }
#pragma unroll
            for (int n = 0; n < 4; n++) {
                f32x4 aA = (f32x4){0.f, 0.f, 0.f, 0.f};
                f32x4 aB = (f32x4){0.f, 0.f, 0.f, 0.f};
#pragma unroll
                for (int ks = 0; ks < 4; ks++) {
                    aA = __builtin_amdgcn_mfma_f32_16x16x32_bf16(afA[ks], bfr[n][ks], aA, 0, 0, 0);
                    aB = __builtin_amdgcn_mfma_f32_16x16x32_bf16(afB[ks], bfr[n][ks], aB, 0, 0, 0);
                }
#pragma unroll
                for (int q = 0; q < 4; q++) {
                    float kA = gelu_sig(aA[q] + bcol[n]);
                    float kB = gelu_sig(aB[q] + bcol[n]);
                    avA[n][q] = fmaf(ca, kA, avA[n][q]);
                    avB[n][q] = fmaf(ca, kB, avB[n][q]);
                    float tA, tB;
                    if (last) { yvA[n][q] = avA[n][q]; tA = avA[n][q];
                                yvB[n][q] = avB[n][q]; tB = avB[n][q]; }
                    else      { tA = fmaf(ct, kA, yvA[n][q]);
                                tB = fmaf(ct, kB, yvB[n][q]); }
                    *(unsigned short*)(pnA + wadr[n][q]) = bfbits(tA);
                    *(unsigned short*)(pnB + wadr[n][q]) = bfbits(tB);
                }
            }
            __syncthreads();
            char* tmp;
            tmp = pcA; pcA = pnA; pnA = tmp;
            tmp = pcB; pcB = pnB; pnB = tmp;
        }
    }
#pragma unroll
    for (int q = 0; q < 4; q++) {
        int ra = rA + lg * 4 + q;
        int rb = rB + lg * 4 + q;
#pragma unroll
        for (int n = 0; n < 4; n++) {
            if (ra < nrows) ybf[(size_t)ra * 128 + hf * 64 + n * 16 + cl] = bfbits(avA[n][q]);
            if (rb < nrows && cB != cA)
                ybf[(size_t)rb * 128 + hf * 64 + n * 16 + cl] = bfbits(avB[n][q]);
        }
    }
}

// ----------------------- hop mean-aggregation (16-lane groups) -------------
__launch_bounds__(256)
__global__ void hop_k(const unsigned* __restrict__ cur, const int* __restrict__ col,
                      const int* __restrict__ offs, const int* __restrict__ deg,
                      unsigned* __restrict__ outbf, int nnodes)
{
    __shared__ int scol[16][16];
    const int gq = threadIdx.x >> 4;
    const int n = blockIdx.x * 16 + gq;
    if (n >= nnodes) return;
    const int l = threadIdx.x & 15;
    const int e0 = offs[n], e1 = offs[n + 1];
    float a0 = 0.f, a1 = 0.f, a2 = 0.f, a3 = 0.f;
    float a4 = 0.f, a5 = 0.f, a6 = 0.f, a7 = 0.f;
    for (int base = e0; base < e1; base += 16) {
        int idx = base + l;
        if (idx < e1) scol[gq][l] = col[idx];
        int cnt = e1 - base; if (cnt > 16) cnt = 16;
#pragma unroll 4
        for (int j = 0; j < cnt; j++) {
            int sj = scol[gq][j];
            uint4 u = *(const uint4*)&cur[(size_t)sj * 64 + l * 4];
            a0 += bf_lo(u.x); a1 += bf_hi(u.x);
            a2 += bf_lo(u.y); a3 += bf_hi(u.y);
            a4 += bf_lo(u.z); a5 += bf_hi(u.z);
            a6 += bf_lo(u.w); a7 += bf_hi(u.w);
        }
    }
    float inv = 1.0f / fmaxf((float)deg[n], 1.0f);
    uint4 o;
    o.x = pack_bf16(a0 * inv, a1 * inv);
    o.y = pack_bf16(a2 * inv, a3 * inv);
    o.z = pack_bf16(a4 * inv, a5 * inv);
    o.w = pack_bf16(a6 * inv, a7 * inv);
    *(uint4*)&outbf[(size_t)n * 64 + l * 4] = o;
}

// --------------- hop3 + hop-attention combine (fused) ----------------------
// computes h3 = mean-gather(cur=h2), then softmax over hop scores and the
// weighted combine, writing fp32 output directly. s2 == cur.
__launch_bounds__(256)
__global__ void hop3f_k(const unsigned* __restrict__ cur, const int* __restrict__ col,
                        const int* __restrict__ offs, const int* __restrict__ deg,
                        const unsigned* __restrict__ s0b, const unsigned* __restrict__ s1b,
                        const float* __restrict__ att, float* __restrict__ outp, int nnodes)
{
    __shared__ int scol[16][16];
    const int gq = threadIdx.x >> 4;
    const int n = blockIdx.x * 16 + gq;
    if (n >= nnodes) return;
    const int l = threadIdx.x & 15;
    const int e0 = offs[n], e1 = offs[n + 1];
    float a[8];
#pragma unroll
    for (int j = 0; j < 8; j++) a[j] = 0.f;
    for (int base = e0; base < e1; base += 16) {
        int idx = base + l;
        if (idx < e1) scol[gq][l] = col[idx];
        int cnt = e1 - base; if (cnt > 16) cnt = 16;
#pragma unroll 4
        for (int j = 0; j < cnt; j++) {
            int sj = scol[gq][j];
            uint4 u = *(const uint4*)&cur[(size_t)sj * 64 + l * 4];
            a[0] += bf_lo(u.x); a[1] += bf_hi(u.x);
            a[2] += bf_lo(u.y); a[3] += bf_hi(u.y);
            a[4] += bf_lo(u.z); a[5] += bf_hi(u.z);
            a[6] += bf_lo(u.w); a[7] += bf_hi(u.w);
        }
    }
    float inv = 1.0f / fmaxf((float)deg[n], 1.0f);
#pragma unroll
    for (int j = 0; j < 8; j++) a[j] *= inv;   // a = h3 row slice (cols l*8..l*8+7)

    // load s0/s1/s2 row slices (sequential)
    size_t b = (size_t)n * 64 + l * 4;
    uint4 u0 = *(const uint4*)&s0b[b];
    uint4 u1 = *(const uint4*)&s1b[b];
    uint4 u2 = *(const uint4*)&cur[b];
    float v0[8] = { bf_lo(u0.x), bf_hi(u0.x), bf_lo(u0.y), bf_hi(u0.y),
                    bf_lo(u0.z), bf_hi(u0.z), bf_lo(u0.w), bf_hi(u0.w) };
    float v1[8] = { bf_lo(u1.x), bf_hi(u1.x), bf_lo(u1.y), bf_hi(u1.y),
                    bf_lo(u1.z), bf_hi(u1.z), bf_lo(u1.w), bf_hi(u1.w) };
    float v2[8] = { bf_lo(u2.x), bf_hi(u2.x), bf_lo(u2.y), bf_hi(u2.y),
                    bf_lo(u2.z), bf_hi(u2.z), bf_lo(u2.w), bf_hi(u2.w) };
    float4 at0 = *(const float4*)&att[l * 8];
    float4 at1 = *(const float4*)&att[l * 8 + 4];
    float atv[8] = { at0.x, at0.y, at0.z, at0.w, at1.x, at1.y, at1.z, at1.w };

    float p0 = 0.f, p1 = 0.f, p2 = 0.f, p3 = 0.f;
#pragma unroll
    for (int j = 0; j < 8; j++) {
        p0 = fmaf(v0[j], atv[j], p0);
        p1 = fmaf(v1[j], atv[j], p1);
        p2 = fmaf(v2[j], atv[j], p2);
        p3 = fmaf(a[j],  atv[j], p3);
    }
#pragma unroll
    for (int mk = 1; mk < 16; mk <<= 1) {
        p0 += __shfl_xor(p0, mk); p1 += __shfl_xor(p1, mk);
        p2 += __shfl_xor(p2, mk); p3 += __shfl_xor(p3, mk);
    }
    float mm = fmaxf(fmaxf(p0, p1), fmaxf(p2, p3));
    float e0e = __expf(p0 - mm), e1e = __expf(p1 - mm);
    float e2e = __expf(p2 - mm), e3e = __expf(p3 - mm);
    float wiv = 1.0f / (e0e + e1e + e2e + e3e);
    float w0 = e0e * wiv, w1 = e1e * wiv, w2 = e2e * wiv, w3 = e3e * wiv;
    float o[8];
#pragma unroll
    for (int j = 0; j < 8; j++)
        o[j] = w0 * v0[j] + w1 * v1[j] + w2 * v2[j] + w3 * a[j];
    size_t ob = (size_t)n * 128 + l * 8;
    *(float4*)&outp[ob]     = make_float4(o[0], o[1], o[2], o[3]);
    *(float4*)&outp[ob + 4] = make_float4(o[4], o[5], o[6], o[7]);
}

// ---------------------------------------------------------------------------
extern "C" void kernel_launch(void* const* d_in, const int* in_sizes, int n_in,
                              void* d_out, int out_size, void* d_ws, size_t ws_size,
                              hipStream_t stream)
{
    const float* x     = (const float*)d_in[0];
    const int*   ei    = (const int*)d_in[1];
    const float* W_in  = (const float*)d_in[2];
    const float* b_in  = (const float*)d_in[3];
    const float* W1    = (const float*)d_in[4];
    const float* a_s1  = (const float*)d_in[5];
    const float* a_d1  = (const float*)d_in[6];
    const float* b1    = (const float*)d_in[7];
    const float* W2    = (const float*)d_in[8];
    const float* a_s2  = (const float*)d_in[9];
    const float* a_d2  = (const float*)d_in[10];
    const float* b2    = (const float*)d_in[11];
    const float* g1    = (const float*)d_in[12];
    const float* be1   = (const float*)d_in[13];
    const float* g2    = (const float*)d_in[14];
    const float* be2   = (const float*)d_in[15];
    const float* W_ode = (const float*)d_in[16];
    const float* b_ode = (const float*)d_in[17];
    const float* att   = (const float*)d_in[18];

    const int N = in_sizes[0] / 128;
    const int E = in_sizes[1] / 2;
    const int* srcv = ei;
    const int* dstv = ei + E;
    const int nb = (N + BSN - 1) / BSN;

    char* wsb = (char*)d_ws;
    size_t off = 0;
    auto alloc = [&](size_t bytes) -> void* {
        void* p = wsb + off;
        off = (off + bytes + 511) & ~(size_t)511;
        return p;
    };
    float*          WnIn   = (float*)alloc(65536);
    float*          WnOde  = (float*)alloc(65536);
    unsigned short* fragb  = (unsigned short*)alloc(32768);
    float*          als    = (float*)alloc((size_t)N * 4 * 4);
    float*          ald    = (float*)alloc((size_t)N * 4 * 4);
    int*            deg    = (int*)alloc((size_t)N * 4);
    int*            bcur   = (int*)alloc((size_t)(nb + 1) * 4);
    int*            offs   = (int*)alloc((size_t)(N + 1) * 4);
    int*            col    = (int*)alloc((size_t)E * 4);
    float*          B0     = (float*)alloc((size_t)N * 128 * 4);
    unsigned*       xhbf   = (unsigned*)alloc((size_t)N * 64 * 4);
    unsigned*       ybf    = (unsigned*)alloc((size_t)N * 64 * 4);
    unsigned*       h2bf   = (unsigned*)alloc((size_t)N * 64 * 4);
    uint2*          pairbuf = (uint2*)ybf;  // aliases ybf; consumed before ybf written

    (void)hipMemsetAsync(deg, 0, (size_t)N * 4, stream);

    sn_k<<<2, 128, 0, stream>>>(W_in, W_ode, WnIn, WnOde);
    frag_k<<<8, 256, 0, stream>>>(WnOde, fragb);
    hist_k<<<(E + 255) / 256, 256, 0, stream>>>(dstv, deg, E, N);
    scan_k<<<1, 1024, 0, stream>>>(deg, offs, N);
    binit_k<<<(nb + 255) / 256, 256, 0, stream>>>(offs, bcur, N, nb);
    scatA_k<<<(E + 4095) / 4096, 256, 0, stream>>>(srcv, dstv, bcur, pairbuf, E, N);
    scatB_k<<<nb, 256, 0, stream>>>(pairbuf, offs, col, N);

    const int gblocks = (N + 127) / 128;
    const int ablocks = (N + 7) / 8;
    const int hblocks = (N + 15) / 16;

    gemm_mfma_k<<<gblocks, 256, 0, stream>>>(x, WnIn, b_in, B0, nullptr, N, 1,
        nullptr, nullptr, nullptr, nullptr);

    gemm_mfma_k<<<gblocks, 256, 0, stream>>>(B0, W1, nullptr, nullptr,
        (unsigned short*)xhbf, N, 0, a_s1, a_d1, als, ald);
    gat_agg2_k<<<ablocks, 256, 0, stream>>>(xhbf, als, ald, col, offs, b1, g1, be1, B0, N);

    gemm_mfma_k<<<gblocks, 256, 0, stream>>>(B0, W2, nullptr, nullptr,
        (unsigned short*)xhbf, N, 0, a_s2, a_d2, als, ald);
    gat_agg2_k<<<ablocks, 256, 0, stream>>>(xhbf, als, ald, col, offs, b2, g2, be2, B0, N);

    const int nchunks = (N + 15) / 16;
    const int oblocks = (nchunks + 1) / 2;
    ode_mfma_k<<<oblocks, 128, 0, stream>>>(B0, fragb, b_ode, (unsigned short*)ybf, N, nchunks);

    hop_k<<<hblocks, 256, 0, stream>>>(ybf,  col, offs, deg, xhbf, N);   // h1
    hop_k<<<hblocks, 256, 0, stream>>>(xhbf, col, offs, deg, h2bf, N);   // h2
    hop3f_k<<<hblocks, 256, 0, stream>>>(h2bf, col, offs, deg, ybf, xhbf,
                                         att, (float*)d_out, N);         // h3 + combine
}

// Round 14
// 632.321 us; speedup vs baseline: 1.0369x; 1.0369x over previous
//
#include <hip/hip_runtime.h>
#include <math.h>

// ---------------------------------------------------------------------------
// TemporalGraphEncoder: N=50000, E=1.6M, D=128, H=4, C=32, HOPS=3
// r14: (1) ODE reverted to r11 config (empirical best: 79us; r12/r13
//      occupancy+ILP experiments both regressed);
//      (2) gat_agg2: no-max softmax (logits bounded ~15 -> exp safe in fp32;
//      softmax shift-invariant) -> pass1 is 4 exp/edge instead of 8+renorm.
// ---------------------------------------------------------------------------

typedef __attribute__((ext_vector_type(8))) short bf16x8;
typedef __attribute__((ext_vector_type(4))) float f32x4;

#define BSN 256   // nodes per bucket in CSR build (bucket id = dst >> 8)

__device__ __forceinline__ float gelu_f(float x) {           // exact (erf)
    return 0.5f * x * (1.0f + erff(x * 0.70710678118654752f));
}
__device__ __forceinline__ float gelu_sig(float x) {         // tanh-form, folded
    float x2 = x * x;
    float f = fmaf(-0.0713548162f, x2, -1.5957691216f);
    float e = __expf(x * f);
    return x * __builtin_amdgcn_rcpf(1.0f + e);
}
__device__ __forceinline__ unsigned pack_bf16(float a, float b) {
    unsigned ua = __float_as_uint(a), ub = __float_as_uint(b);
    ua += 0x7fffu + ((ua >> 16) & 1u);
    ub += 0x7fffu + ((ub >> 16) & 1u);
    return (ua >> 16) | (ub & 0xffff0000u);
}
__device__ __forceinline__ unsigned short bfbits(float x) {
    unsigned u = __float_as_uint(x);
    u += 0x7fffu + ((u >> 16) & 1u);
    return (unsigned short)(u >> 16);
}
__device__ __forceinline__ float bf_lo(unsigned u) { return __uint_as_float(u << 16); }
__device__ __forceinline__ float bf_hi(unsigned u) { return __uint_as_float(u & 0xffff0000u); }
// XOR swizzle for 256B-row-stride LDS tiles (16B granule)
__device__ __forceinline__ int swz(int byte) { return byte ^ (((byte >> 8) & 15) << 4); }

// ---------------------- spectral norm (power iteration) --------------------
__launch_bounds__(128, 1)
__global__ void sn_k(const float* __restrict__ Win, const float* __restrict__ Wode,
                     float* __restrict__ WnIn, float* __restrict__ WnOde)
{
    __shared__ float Ws[128 * 128];
    __shared__ float Wt[128 * 128];
    __shared__ float red[128];
    const float* W  = (blockIdx.x == 0) ? Win  : Wode;
    float*       Wn = (blockIdx.x == 0) ? WnIn : WnOde;
    const int t = threadIdx.x;

    for (int i = t * 4; i < 16384; i += 512) {
        float4 v = *(const float4*)&W[i];
        *(float4*)&Ws[i] = v;
        int r = i >> 7, c = i & 127;
        Wt[(c + 0) * 128 + r] = v.x;
        Wt[(c + 1) * 128 + r] = v.y;
        Wt[(c + 2) * 128 + r] = v.z;
        Wt[(c + 3) * 128 + r] = v.w;
    }
    __syncthreads();

    float u = 0.088388347648318447f;  // 1/sqrt(128)
    float v = 0.0f;
    for (int it = 0; it < 5; it++) {
        red[t] = u; __syncthreads();
        float vv = 0.f;
        for (int i = 0; i < 128; i++) vv = fmaf(Ws[i * 128 + t], red[i], vv);
        __syncthreads();
        red[t] = vv * vv; __syncthreads();
        for (int s = 64; s > 0; s >>= 1) { if (t < s) red[t] += red[t + s]; __syncthreads(); }
        float nv = sqrtf(red[0]) + 1e-12f;
        v = vv / nv;
        __syncthreads();
        red[t] = v; __syncthreads();
        float uu = 0.f;
        for (int i = 0; i < 128; i++) uu = fmaf(Wt[i * 128 + t], red[i], uu);
        __syncthreads();
        red[t] = uu * uu; __syncthreads();
        for (int s = 64; s > 0; s >>= 1) { if (t < s) red[t] += red[t + s]; __syncthreads(); }
        float nu = sqrtf(red[0]) + 1e-12f;
        u = uu / nu;
        __syncthreads();
    }
    red[t] = v; __syncthreads();
    float wv = 0.f;
    for (int i = 0; i < 128; i++) wv = fmaf(Wt[i * 128 + t], red[i], wv);
    __syncthreads();
    red[t] = u * wv; __syncthreads();
    for (int s = 64; s > 0; s >>= 1) { if (t < s) red[t] += red[t + s]; __syncthreads(); }
    float inv = 1.0f / (red[0] + 1e-12f);
    __syncthreads();
    for (int i = t * 4; i < 16384; i += 512) {
        float4 w = *(const float4*)&Ws[i];
        w.x *= inv; w.y *= inv; w.z *= inv; w.w *= inv;
        *(float4*)&Wn[i] = w;
    }
}

// ---------------- pack W_ode^T into B-fragment order (bf16, global) --------
__launch_bounds__(256)
__global__ void frag_k(const float* __restrict__ Wn, unsigned short* __restrict__ frag)
{
    int f = blockIdx.x * 256 + threadIdx.x;
    if (f >= 2048) return;
    int lane = f & 63, ks = (f >> 6) & 3, m = f >> 8;
    int cl = lane & 15, lg = lane >> 4;
    unsigned short tmp[8];
#pragma unroll
    for (int j = 0; j < 8; j++)
        tmp[j] = bfbits(Wn[(ks * 32 + lg * 8 + j) * 128 + m * 16 + cl]);
    *(uint4*)&frag[(size_t)f * 8] = *(uint4*)tmp;
}

// ------------------------------ CSR build ----------------------------------
__global__ void hist_k(const int* __restrict__ dst, int* __restrict__ deg, int E, int N)
{
    int e = blockIdx.x * blockDim.x + threadIdx.x;
    if (e < E) {
        int d = dst[e];
        d = (d < 0) ? 0 : (d >= N ? N - 1 : d);
        atomicAdd(&deg[d], 1);
    }
}

__launch_bounds__(1024, 1)
__global__ void scan_k(const int* __restrict__ deg, int* __restrict__ offs, int n)
{
    __shared__ int part[1024];
    const int t = threadIdx.x;
    const int chunk = (n + 1023) >> 10;
    int lo = t * chunk; if (lo > n) lo = n;
    int hi = lo + chunk; if (hi > n) hi = n;
    int s = 0;
    for (int i = lo; i < hi; i++) s += deg[i];
    part[t] = s; __syncthreads();
    for (int d = 1; d < 1024; d <<= 1) {
        int v = (t >= d) ? part[t - d] : 0;
        __syncthreads();
        part[t] += v;
        __syncthreads();
    }
    int run = (t == 0) ? 0 : part[t - 1];
    for (int i = lo; i < hi; i++) { offs[i] = run; run += deg[i]; }
    if (t == 1023) offs[n] = run;
}

__global__ void binit_k(const int* __restrict__ offs, int* __restrict__ bcur, int N, int nb)
{
    int b = blockIdx.x * blockDim.x + threadIdx.x;
    if (b < nb) {
        int n = b * BSN; if (n > N) n = N;
        bcur[b] = offs[n];
    }
}

// pass A: block-level multisplit of edges into bucket regions of pairbuf.
__launch_bounds__(256, 2)
__global__ void scatA_k(const int* __restrict__ src, const int* __restrict__ dst,
                        int* __restrict__ bcur, uint2* __restrict__ pairbuf, int E, int N)
{
    __shared__ int cnt[256];
    __shared__ int sc[256];
    __shared__ int ebase[256];
    __shared__ int delta[256];
    __shared__ uint2 pr[4096];
    __shared__ unsigned char bid[4096];
    const int t = threadIdx.x;
    const int e0 = blockIdx.x * 4096;

    int s[16], d[16], rk[16], bb[16];
    cnt[t] = 0;
    __syncthreads();
#pragma unroll
    for (int i = 0; i < 16; i++) {
        int e = e0 + i * 256 + t;
        if (e < E) {
            int dd = dst[e]; dd = (dd < 0) ? 0 : (dd >= N ? N - 1 : dd);
            int ss = src[e]; ss = (ss < 0) ? 0 : (ss >= N ? N - 1 : ss);
            s[i] = ss; d[i] = dd; bb[i] = dd >> 8;
            rk[i] = atomicAdd(&cnt[bb[i]], 1);
        } else bb[i] = -1;
    }
    __syncthreads();
    sc[t] = cnt[t]; __syncthreads();
    for (int st = 1; st < 256; st <<= 1) {
        int v = (t >= st) ? sc[t - st] : 0;
        __syncthreads();
        sc[t] += v;
        __syncthreads();
    }
    int excl = sc[t] - cnt[t];
    int gbase = (cnt[t] > 0) ? atomicAdd(&bcur[t], cnt[t]) : 0;
    ebase[t] = excl;
    delta[t] = gbase - excl;
    __syncthreads();
#pragma unroll
    for (int i = 0; i < 16; i++) {
        if (bb[i] >= 0) {
            int slot = ebase[bb[i]] + rk[i];
            pr[slot] = make_uint2((unsigned)s[i], (unsigned)d[i]);
            bid[slot] = (unsigned char)bb[i];
        }
    }
    __syncthreads();
    const int total = sc[255];
    for (int i2 = t; i2 < total; i2 += 256) {
        int b = bid[i2];
        pairbuf[delta[b] + i2] = pr[i2];
    }
}

// pass B: one block per bucket; finalize col with LDS node cursors.
__launch_bounds__(256, 4)
__global__ void scatB_k(const uint2* __restrict__ pairbuf, const int* __restrict__ offs,
                        int* __restrict__ col, int N)
{
    __shared__ int cur[BSN];
    const int b = blockIdx.x;
    const int n0 = b * BSN;
    const int t = threadIdx.x;
    int nn = N - n0; if (nn > BSN) nn = BSN;
    if (t < nn) cur[t] = offs[n0 + t];
    __syncthreads();
    const int es = offs[n0], ee = offs[n0 + nn];
    for (int e = es + t; e < ee; e += 256) {
        uint2 p = pairbuf[e];
        int pos = atomicAdd(&cur[(int)p.y - n0], 1);
        col[pos] = (int)p.x;
    }
}

// ------------------------ GEMM 128 (bf16 MFMA) -----------------------------
__launch_bounds__(256, 2)
__global__ void gemm_mfma_k(const float* __restrict__ in, const float* __restrict__ W,
                            const float* __restrict__ bias, float* __restrict__ out_f32,
                            unsigned short* __restrict__ out_bf, int nrows, int mode,
                            const float* __restrict__ a_s, const float* __restrict__ a_d,
                            float* __restrict__ als, float* __restrict__ ald)
{
    __shared__ unsigned short Wt[128 * 128];
    __shared__ unsigned short As[128 * 128];
    const int t = threadIdx.x;
    const int w = t >> 6, lane = t & 63;
    const int cl = lane & 15, lg = lane >> 4;
    const int r0 = blockIdx.x * 128;

    for (int i = t; i < 16384; i += 256) {
        int k = i >> 7, c = i & 127;
        *(unsigned short*)((char*)Wt + swz((c << 8) + (k << 1))) = bfbits(W[i]);
    }
    for (int i2 = t; i2 < 4096; i2 += 256) {
        int r = i2 >> 5, k0 = (i2 & 31) * 4;
        int rc = r0 + r; if (rc > nrows - 1) rc = nrows - 1;
        float4 v = *(const float4*)&in[(size_t)rc * 128 + k0];
        *(uint2*)((char*)As + swz((r << 8) + (k0 << 1))) =
            make_uint2(pack_bf16(v.x, v.y), pack_bf16(v.z, v.w));
    }
    __syncthreads();

    bf16x8 af[2][4];
#pragma unroll
    for (int rt = 0; rt < 2; rt++)
#pragma unroll
        for (int ks = 0; ks < 4; ks++)
            af[rt][ks] = *(const bf16x8*)((char*)As +
                           swz((w * 32 + rt * 16 + cl) * 256 + ks * 64 + lg * 16));

    f32x4 acc[2][8];
#pragma unroll
    for (int rt = 0; rt < 2; rt++)
#pragma unroll
        for (int n = 0; n < 8; n++) acc[rt][n] = (f32x4){0.f, 0.f, 0.f, 0.f};

#pragma unroll
    for (int n = 0; n < 8; n++) {
#pragma unroll
        for (int ks = 0; ks < 4; ks++) {
            bf16x8 bf = *(const bf16x8*)((char*)Wt +
                          swz((n * 16 + cl) * 256 + ks * 64 + lg * 16));
            acc[0][n] = __builtin_amdgcn_mfma_f32_16x16x32_bf16(af[0][ks], bf, acc[0][n], 0, 0, 0);
            acc[1][n] = __builtin_amdgcn_mfma_f32_16x16x32_bf16(af[1][ks], bf, acc[1][n], 0, 0, 0);
        }
    }

    if (mode == 0) {
        float asv[4][2], adv[4][2];
#pragma unroll
        for (int h = 0; h < 4; h++) {
            asv[h][0] = a_s[h * 32 + cl];      asv[h][1] = a_s[h * 32 + 16 + cl];
            adv[h][0] = a_d[h * 32 + cl];      adv[h][1] = a_d[h * 32 + 16 + cl];
        }
#pragma unroll
        for (int rt = 0; rt < 2; rt++) {
#pragma unroll
            for (int q = 0; q < 4; q++) {
                int row = r0 + w * 32 + rt * 16 + lg * 4 + q;
                float sh[4], dh[4];
#pragma unroll
                for (int h = 0; h < 4; h++) {
                    sh[h] = acc[rt][2 * h][q] * asv[h][0] + acc[rt][2 * h + 1][q] * asv[h][1];
                    dh[h] = acc[rt][2 * h][q] * adv[h][0] + acc[rt][2 * h + 1][q] * adv[h][1];
                }
#pragma unroll
                for (int mk = 1; mk < 16; mk <<= 1) {
#pragma unroll
                    for (int h = 0; h < 4; h++) {
                        sh[h] += __shfl_xor(sh[h], mk);
                        dh[h] += __shfl_xor(dh[h], mk);
                    }
                }
                if (cl == 0 && row < nrows) {
#pragma unroll
                    for (int h = 0; h < 4; h++) {
                        als[(size_t)row * 4 + h] = sh[h];
                        ald[(size_t)row * 4 + h] = dh[h];
                    }
                }
            }
#pragma unroll
            for (int q = 0; q < 4; q++) {
                int row = r0 + w * 32 + rt * 16 + lg * 4 + q;
                if (row < nrows) {
#pragma unroll
                    for (int n = 0; n < 8; n++)
                        out_bf[(size_t)row * 128 + n * 16 + cl] = bfbits(acc[rt][n][q]);
                }
            }
        }
    } else {
        float bc[8];
#pragma unroll
        for (int n = 0; n < 8; n++) bc[n] = bias[n * 16 + cl];
#pragma unroll
        for (int rt = 0; rt < 2; rt++)
#pragma unroll
            for (int q = 0; q < 4; q++) {
                int row = r0 + w * 32 + rt * 16 + lg * 4 + q;
                if (row < nrows) {
#pragma unroll
                    for (int n = 0; n < 8; n++)
                        out_f32[(size_t)row * 128 + n * 16 + cl] =
                            gelu_f(acc[rt][n][q] + bc[n]);
                }
            }
    }
}

// ----------------------- GAT aggregation (no-max softmax) ------------------
// logits bounded (LN'd activations, 1/sqrt(C) weights) -> exp safe in fp32;
// softmax is shift-invariant so the per-dst max subtraction is unnecessary.
__launch_bounds__(256)
__global__ void gat_agg2_k(const unsigned* __restrict__ xhbf, const float* __restrict__ als,
                           const float* __restrict__ ald, const int* __restrict__ col,
                           const int* __restrict__ offs, const float* __restrict__ bias,
                           const float* __restrict__ g, const float* __restrict__ be,
                           float* __restrict__ hout, int nnodes)
{
    __shared__ float alph[8][32][4];
    __shared__ int   scol[8][32];
    const int gq = threadIdx.x >> 5;
    const int n = blockIdx.x * 8 + gq;
    if (n >= nnodes) return;
    const int l = threadIdx.x & 31;
    const int e0 = offs[n], e1 = offs[n + 1];
    const float4 aldv = *(const float4*)&ald[(size_t)n * 4];

    // pass 1: sum of exp(leaky(logit)) per head (no max subtraction)
    float s0 = 0.f, s1 = 0.f, s2 = 0.f, s3 = 0.f;
    for (int i = e0 + l; i < e1; i += 32) {
        int sv = col[i];
        float4 av = *(const float4*)&als[(size_t)sv * 4];
        float l0 = av.x + aldv.x; l0 = l0 > 0.f ? l0 : 0.2f * l0;
        float l1 = av.y + aldv.y; l1 = l1 > 0.f ? l1 : 0.2f * l1;
        float l2 = av.z + aldv.z; l2 = l2 > 0.f ? l2 : 0.2f * l2;
        float l3 = av.w + aldv.w; l3 = l3 > 0.f ? l3 : 0.2f * l3;
        s0 += __expf(l0); s1 += __expf(l1); s2 += __expf(l2); s3 += __expf(l3);
    }
#pragma unroll
    for (int mk = 1; mk < 32; mk <<= 1) {
        s0 += __shfl_xor(s0, mk); s1 += __shfl_xor(s1, mk);
        s2 += __shfl_xor(s2, mk); s3 += __shfl_xor(s3, mk);
    }
    const float i0 = __builtin_amdgcn_rcpf(s0 + 1e-16f);
    const float i1 = __builtin_amdgcn_rcpf(s1 + 1e-16f);
    const float i2 = __builtin_amdgcn_rcpf(s2 + 1e-16f);
    const float i3 = __builtin_amdgcn_rcpf(s3 + 1e-16f);

    // pass 2: alpha-weighted gather of xh
    const int hh = l >> 3;
    float a0 = 0.f, a1 = 0.f, a2 = 0.f, a3 = 0.f;
    for (int base = e0; base < e1; base += 32) {
        int idx = base + l;
        if (idx < e1) {
            int sv = col[idx];
            float4 av = *(const float4*)&als[(size_t)sv * 4];
            float l0 = av.x + aldv.x; l0 = l0 > 0.f ? l0 : 0.2f * l0;
            float l1 = av.y + aldv.y; l1 = l1 > 0.f ? l1 : 0.2f * l1;
            float l2 = av.z + aldv.z; l2 = l2 > 0.f ? l2 : 0.2f * l2;
            float l3 = av.w + aldv.w; l3 = l3 > 0.f ? l3 : 0.2f * l3;
            float4 a4;
            a4.x = __expf(l0) * i0;
            a4.y = __expf(l1) * i1;
            a4.z = __expf(l2) * i2;
            a4.w = __expf(l3) * i3;
            *(float4*)&alph[gq][l][0] = a4;
            scol[gq][l] = sv;
        }
        int cnt = e1 - base; if (cnt > 32) cnt = 32;
#pragma unroll 4
        for (int j = 0; j < cnt; j++) {
            int sj = scol[gq][j];
            float aj = alph[gq][j][hh];
            uint2 u = *(const uint2*)&xhbf[(size_t)sj * 64 + l * 2];
            a0 = fmaf(aj, bf_lo(u.x), a0);
            a1 = fmaf(aj, bf_hi(u.x), a1);
            a2 = fmaf(aj, bf_lo(u.y), a2);
            a3 = fmaf(aj, bf_hi(u.y), a3);
        }
    }

    const int c0 = l * 4;
    float4 bv = *(const float4*)&bias[c0];
    float v0 = gelu_f(a0 + bv.x);
    float v1 = gelu_f(a1 + bv.y);
    float v2 = gelu_f(a2 + bv.z);
    float v3 = gelu_f(a3 + bv.w);
    float sum = v0 + v1 + v2 + v3;
#pragma unroll
    for (int mk = 1; mk < 32; mk <<= 1) sum += __shfl_xor(sum, mk);
    float mean = sum * (1.0f / 128.0f);
    float d0 = v0 - mean, d1 = v1 - mean, d2 = v2 - mean, d3 = v3 - mean;
    float vs = d0 * d0 + d1 * d1 + d2 * d2 + d3 * d3;
#pragma unroll
    for (int mk = 1; mk < 32; mk <<= 1) vs += __shfl_xor(vs, mk);
    float rstd = rsqrtf(vs * (1.0f / 128.0f) + 1e-5f);
    float4 gv = *(const float4*)&g[c0];
    float4 ev = *(const float4*)&be[c0];
    float4 o;
    o.x = d0 * rstd * gv.x + ev.x;
    o.y = d1 * rstd * gv.y + ev.y;
    o.z = d2 * rstd * gv.z + ev.z;
    o.w = d3 * rstd * gv.w + ev.w;
    *(float4*)&hout[(size_t)n * 128 + c0] = o;
}

// ----------------------- fused RK4 ODE (bf16 MFMA, r11 config) -------------
// 128 threads = one wave-pair. B-frags in registers from pre-packed global
// buffer (L2-hot). LDS = 8KB t dbuf. One block per chunk (empirical best).
__launch_bounds__(128, 2)
__global__ void ode_mfma_k(const float* __restrict__ yin,
                           const unsigned short* __restrict__ frag,
                           const float* __restrict__ bias,
                           unsigned short* __restrict__ ybf,
                           int nrows, int nchunks)
{
    __shared__ unsigned short tl[2][16 * 128];   // double buffer, 4KB each
    const int t = threadIdx.x;
    const int hf = t >> 6, lane = t & 63;
    const int cl = lane & 15, lg = lane >> 4;

    float bcol[4];
#pragma unroll
    for (int n = 0; n < 4; n++) bcol[n] = bias[(hf * 4 + n) * 16 + cl];

    bf16x8 bfr[4][4];
#pragma unroll
    for (int n = 0; n < 4; n++)
#pragma unroll
        for (int ks = 0; ks < 4; ks++)
            bfr[n][ks] = *(const bf16x8*)&frag[((size_t)(((hf * 4 + n) * 4 + ks) * 64 + lane)) * 8];

    int radr[4], wadr[4][4];
#pragma unroll
    for (int ks = 0; ks < 4; ks++)
        radr[ks] = swz(cl * 256 + ks * 64 + lg * 16);
#pragma unroll
    for (int n = 0; n < 4; n++)
#pragma unroll
        for (int q = 0; q < 4; q++)
            wadr[n][q] = swz((lg * 4 + q) * 256 + ((hf * 4 + n) * 16 + cl) * 2);

    const float dt = 0.25f;
    char* tb0 = (char*)&tl[0][0];
    char* tb1 = (char*)&tl[1][0];

    int chunk = blockIdx.x;
    if (chunk > nchunks - 1) chunk = nchunks - 1;
    const int r0 = chunk * 16;

    for (int i2 = t; i2 < 512; i2 += 128) {
        int r = i2 >> 5, k0 = (i2 & 31) * 4;
        int rc = r0 + r; if (rc > nrows - 1) rc = nrows - 1;
        float4 v = *(const float4*)&yin[(size_t)rc * 128 + k0];
        *(uint2*)(tb0 + swz(r * 256 + k0 * 2)) =
            make_uint2(pack_bf16(v.x, v.y), pack_bf16(v.z, v.w));
    }
    float yv[4][4], av[4][4];
#pragma unroll
    for (int q = 0; q < 4; q++) {
        int rc = r0 + lg * 4 + q; if (rc > nrows - 1) rc = nrows - 1;
        const float* rp = &yin[(size_t)rc * 128 + hf * 64 + cl];
#pragma unroll
        for (int n = 0; n < 4; n++) { yv[n][q] = rp[n * 16]; av[n][q] = yv[n][q]; }
    }
    __syncthreads();

    char* pc = tb0;
    char* pn = tb1;
#pragma unroll 1
    for (int step = 0; step < 4; step++) {
#pragma unroll 1
        for (int st = 0; st < 4; st++) {
            const float ca = (st == 0 || st == 3) ? dt / 6.f : dt / 3.f;
            const float ct = (st < 2) ? dt * 0.5f : dt;
            const bool last = (st == 3);
            bf16x8 af[4];
#pragma unroll
            for (int ks = 0; ks < 4; ks++)
                af[ks] = *(const bf16x8*)(pc + radr[ks]);
            f32x4 acc[4];
#pragma unroll
            for (int n = 0; n < 4; n++) {
                acc[n] = (f32x4){0.f, 0.f, 0.f, 0.f};
#pragma unroll
                for (int ks = 0; ks < 4; ks++)
                    acc[n] = __builtin_amdgcn_mfma_f32_16x16x32_bf16(af[ks], bfr[n][ks], acc[n], 0, 0, 0);
            }
#pragma unroll
            for (int n = 0; n < 4; n++) {
#pragma unroll
                for (int q = 0; q < 4; q++) {
                    float kk = gelu_sig(acc[n][q] + bcol[n]);
                    av[n][q] = fmaf(ca, kk, av[n][q]);
                    float tn;
                    if (last) { yv[n][q] = av[n][q]; tn = av[n][q]; }
                    else      { tn = fmaf(ct, kk, yv[n][q]); }
                    *(unsigned short*)(pn + wadr[n][q]) = bfbits(tn);
                }
            }
            __syncthreads();
            char* tmp = pc; pc = pn; pn = tmp;
        }
    }
#pragma unroll
    for (int q = 0; q < 4; q++) {
        int rg = r0 + lg * 4 + q;
        if (rg < nrows) {
#pragma unroll
            for (int n = 0; n < 4; n++)
                ybf[(size_t)rg * 128 + hf * 64 + n * 16 + cl] = bfbits(av[n][q]);
        }
    }
}

// ----------------------- hop mean-aggregation (16-lane groups) -------------
__launch_bounds__(256)
__global__ void hop_k(const unsigned* __restrict__ cur, const int* __restrict__ col,
                      const int* __restrict__ offs, const int* __restrict__ deg,
                      unsigned* __restrict__ outbf, int nnodes)
{
    __shared__ int scol[16][16];
    const int gq = threadIdx.x >> 4;
    const int n = blockIdx.x * 16 + gq;
    if (n >= nnodes) return;
    const int l = threadIdx.x & 15;
    const int e0 = offs[n], e1 = offs[n + 1];
    float a0 = 0.f, a1 = 0.f, a2 = 0.f, a3 = 0.f;
    float a4 = 0.f, a5 = 0.f, a6 = 0.f, a7 = 0.f;
    for (int base = e0; base < e1; base += 16) {
        int idx = base + l;
        if (idx < e1) scol[gq][l] = col[idx];
        int cnt = e1 - base; if (cnt > 16) cnt = 16;
#pragma unroll 4
        for (int j = 0; j < cnt; j++) {
            int sj = scol[gq][j];
            uint4 u = *(const uint4*)&cur[(size_t)sj * 64 + l * 4];
            a0 += bf_lo(u.x); a1 += bf_hi(u.x);
            a2 += bf_lo(u.y); a3 += bf_hi(u.y);
            a4 += bf_lo(u.z); a5 += bf_hi(u.z);
            a6 += bf_lo(u.w); a7 += bf_hi(u.w);
        }
    }
    float inv = 1.0f / fmaxf((float)deg[n], 1.0f);
    uint4 o;
    o.x = pack_bf16(a0 * inv, a1 * inv);
    o.y = pack_bf16(a2 * inv, a3 * inv);
    o.z = pack_bf16(a4 * inv, a5 * inv);
    o.w = pack_bf16(a6 * inv, a7 * inv);
    *(uint4*)&outbf[(size_t)n * 64 + l * 4] = o;
}

// --------------- hop3 + hop-attention combine (fused) ----------------------
__launch_bounds__(256)
__global__ void hop3f_k(const unsigned* __restrict__ cur, const int* __restrict__ col,
                        const int* __restrict__ offs, const int* __restrict__ deg,
                        const unsigned* __restrict__ s0b, const unsigned* __restrict__ s1b,
                        const float* __restrict__ att, float* __restrict__ outp, int nnodes)
{
    __shared__ int scol[16][16];
    const int gq = threadIdx.x >> 4;
    const int n = blockIdx.x * 16 + gq;
    if (n >= nnodes) return;
    const int l = threadIdx.x & 15;
    const int e0 = offs[n], e1 = offs[n + 1];
    float a[8];
#pragma unroll
    for (int j = 0; j < 8; j++) a[j] = 0.f;
    for (int base = e0; base < e1; base += 16) {
        int idx = base + l;
        if (idx < e1) scol[gq][l] = col[idx];
        int cnt = e1 - base; if (cnt > 16) cnt = 16;
#pragma unroll 4
        for (int j = 0; j < cnt; j++) {
            int sj = scol[gq][j];
            uint4 u = *(const uint4*)&cur[(size_t)sj * 64 + l * 4];
            a[0] += bf_lo(u.x); a[1] += bf_hi(u.x);
            a[2] += bf_lo(u.y); a[3] += bf_hi(u.y);
            a[4] += bf_lo(u.z); a[5] += bf_hi(u.z);
            a[6] += bf_lo(u.w); a[7] += bf_hi(u.w);
        }
    }
    float inv = 1.0f / fmaxf((float)deg[n], 1.0f);
#pragma unroll
    for (int j = 0; j < 8; j++) a[j] *= inv;

    size_t b = (size_t)n * 64 + l * 4;
    uint4 u0 = *(const uint4*)&s0b[b];
    uint4 u1 = *(const uint4*)&s1b[b];
    uint4 u2 = *(const uint4*)&cur[b];
    float v0[8] = { bf_lo(u0.x), bf_hi(u0.x), bf_lo(u0.y), bf_hi(u0.y),
                    bf_lo(u0.z), bf_hi(u0.z), bf_lo(u0.w), bf_hi(u0.w) };
    float v1[8] = { bf_lo(u1.x), bf_hi(u1.x), bf_lo(u1.y), bf_hi(u1.y),
                    bf_lo(u1.z), bf_hi(u1.z), bf_lo(u1.w), bf_hi(u1.w) };
    float v2[8] = { bf_lo(u2.x), bf_hi(u2.x), bf_lo(u2.y), bf_hi(u2.y),
                    bf_lo(u2.z), bf_hi(u2.z), bf_lo(u2.w), bf_hi(u2.w) };
    float4 at0 = *(const float4*)&att[l * 8];
    float4 at1 = *(const float4*)&att[l * 8 + 4];
    float atv[8] = { at0.x, at0.y, at0.z, at0.w, at1.x, at1.y, at1.z, at1.w };

    float p0 = 0.f, p1 = 0.f, p2 = 0.f, p3 = 0.f;
#pragma unroll
    for (int j = 0; j < 8; j++) {
        p0 = fmaf(v0[j], atv[j], p0);
        p1 = fmaf(v1[j], atv[j], p1);
        p2 = fmaf(v2[j], atv[j], p2);
        p3 = fmaf(a[j],  atv[j], p3);
    }
#pragma unroll
    for (int mk = 1; mk < 16; mk <<= 1) {
        p0 += __shfl_xor(p0, mk); p1 += __shfl_xor(p1, mk);
        p2 += __shfl_xor(p2, mk); p3 += __shfl_xor(p3, mk);
    }
    float mm = fmaxf(fmaxf(p0, p1), fmaxf(p2, p3));
    float e0e = __expf(p0 - mm), e1e = __expf(p1 - mm);
    float e2e = __expf(p2 - mm), e3e = __expf(p3 - mm);
    float wiv = 1.0f / (e0e + e1e + e2e + e3e);
    float w0 = e0e * wiv, w1 = e1e * wiv, w2 = e2e * wiv, w3 = e3e * wiv;
    float o[8];
#pragma unroll
    for (int j = 0; j < 8; j++)
        o[j] = w0 * v0[j] + w1 * v1[j] + w2 * v2[j] + w3 * a[j];
    size_t ob = (size_t)n * 128 + l * 8;
    *(float4*)&outp[ob]     = make_float4(o[0], o[1], o[2], o[3]);
    *(float4*)&outp[ob + 4] = make_float4(o[4], o[5], o[6], o[7]);
}

// ---------------------------------------------------------------------------
extern "C" void kernel_launch(void* const* d_in, const int* in_sizes, int n_in,
                              void* d_out, int out_size, void* d_ws, size_t ws_size,
                              hipStream_t stream)
{
    const float* x     = (const float*)d_in[0];
    const int*   ei    = (const int*)d_in[1];
    const float* W_in  = (const float*)d_in[2];
    const float* b_in  = (const float*)d_in[3];
    const float* W1    = (const float*)d_in[4];
    const float* a_s1  = (const float*)d_in[5];
    const float* a_d1  = (const float*)d_in[6];
    const float* b1    = (const float*)d_in[7];
    const float* W2    = (const float*)d_in[8];
    const float* a_s2  = (const float*)d_in[9];
    const float* a_d2  = (const float*)d_in[10];
    const float* b2    = (const float*)d_in[11];
    const float* g1    = (const float*)d_in[12];
    const float* be1   = (const float*)d_in[13];
    const float* g2    = (const float*)d_in[14];
    const float* be2   = (const float*)d_in[15];
    const float* W_ode = (const float*)d_in[16];
    const float* b_ode = (const float*)d_in[17];
    const float* att   = (const float*)d_in[18];

    const int N = in_sizes[0] / 128;
    const int E = in_sizes[1] / 2;
    const int* srcv = ei;
    const int* dstv = ei + E;
    const int nb = (N + BSN - 1) / BSN;

    char* wsb = (char*)d_ws;
    size_t off = 0;
    auto alloc = [&](size_t bytes) -> void* {
        void* p = wsb + off;
        off = (off + bytes + 511) & ~(size_t)511;
        return p;
    };
    float*          WnIn   = (float*)alloc(65536);
    float*          WnOde  = (float*)alloc(65536);
    unsigned short* fragb  = (unsigned short*)alloc(32768);
    float*          als    = (float*)alloc((size_t)N * 4 * 4);
    float*          ald    = (float*)alloc((size_t)N * 4 * 4);
    int*            deg    = (int*)alloc((size_t)N * 4);
    int*            bcur   = (int*)alloc((size_t)(nb + 1) * 4);
    int*            offs   = (int*)alloc((size_t)(N + 1) * 4);
    int*            col    = (int*)alloc((size_t)E * 4);
    float*          B0     = (float*)alloc((size_t)N * 128 * 4);
    unsigned*       xhbf   = (unsigned*)alloc((size_t)N * 64 * 4);
    unsigned*       ybf    = (unsigned*)alloc((size_t)N * 64 * 4);
    unsigned*       h2bf   = (unsigned*)alloc((size_t)N * 64 * 4);
    uint2*          pairbuf = (uint2*)ybf;  // aliases ybf; consumed before ybf written

    (void)hipMemsetAsync(deg, 0, (size_t)N * 4, stream);

    sn_k<<<2, 128, 0, stream>>>(W_in, W_ode, WnIn, WnOde);
    frag_k<<<8, 256, 0, stream>>>(WnOde, fragb);
    hist_k<<<(E + 255) / 256, 256, 0, stream>>>(dstv, deg, E, N);
    scan_k<<<1, 1024, 0, stream>>>(deg, offs, N);
    binit_k<<<(nb + 255) / 256, 256, 0, stream>>>(offs, bcur, N, nb);
    scatA_k<<<(E + 4095) / 4096, 256, 0, stream>>>(srcv, dstv, bcur, pairbuf, E, N);
    scatB_k<<<nb, 256, 0, stream>>>(pairbuf, offs, col, N);

    const int gblocks = (N + 127) / 128;
    const int ablocks = (N + 7) / 8;
    const int hblocks = (N + 15) / 16;

    gemm_mfma_k<<<gblocks, 256, 0, stream>>>(x, WnIn, b_in, B0, nullptr, N, 1,
        nullptr, nullptr, nullptr, nullptr);

    gemm_mfma_k<<<gblocks, 256, 0, stream>>>(B0, W1, nullptr, nullptr,
        (unsigned short*)xhbf, N, 0, a_s1, a_d1, als, ald);
    gat_agg2_k<<<ablocks, 256, 0, stream>>>(xhbf, als, ald, col, offs, b1, g1, be1, B0, N);

    gemm_mfma_k<<<gblocks, 256, 0, stream>>>(B0, W2, nullptr, nullptr,
        (unsigned short*)xhbf, N, 0, a_s2, a_d2, als, ald);
    gat_agg2_k<<<ablocks, 256, 0, stream>>>(xhbf, als, ald, col, offs, b2, g2, be2, B0, N);

    const int nchunks = (N + 15) / 16;
    ode_mfma_k<<<nchunks, 128, 0, stream>>>(B0, fragb, b_ode, (unsigned short*)ybf, N, nchunks);

    hop_k<<<hblocks, 256, 0, stream>>>(ybf,  col, offs, deg, xhbf, N);   // h1
    hop_k<<<hblocks, 256, 0, stream>>>(xhbf, col, offs, deg, h2bf, N);   // h2
    hop3f_k<<<hblocks, 256, 0, stream>>>(h2bf, col, offs, deg, ybf, xhbf,
                                         att, (float*)d_out, N);         // h3 + combine
}